// Round 2
// baseline (75.925 us; speedup 1.0000x reference)
//
#include <hip/hip_runtime.h>
#include <hip/hip_bf16.h>

#define N 8192
#define D 128
#define JC 8                 // j-chunks (grid parallelism over j)
#define BM 64                // rows per block
#define NRB (N / BM)         // 128 row-blocks
#define JCH (N / JC)         // 1024 columns per chunk
#define NLBL 100             // labels are in [0, 100)
#define LCH 32               // label-sum chunks
#define LROWS (N / LCH)      // 256 rows per label-sum chunk

#define K1F 14.426950408889634f    // 10 * log2(e)
#define K0F (-14.426950408889634f)

#if __has_builtin(__builtin_amdgcn_exp2f)
#define EXP2(x) __builtin_amdgcn_exp2f(x)
#else
#define EXP2(x) exp2f(x)
#endif

typedef __attribute__((ext_vector_type(8))) short bf16x8;
typedef __attribute__((ext_vector_type(4))) float f32x4;

// ---------------- Stage 0: row-normalize z -> bf16 zn, plus self-dot d_ii ----
__global__ __launch_bounds__(256) void znorm_kernel(const float* __restrict__ z,
                                                    ushort* __restrict__ zn,
                                                    float* __restrict__ dii) {
    const int wid  = threadIdx.x >> 6;
    const int lane = threadIdx.x & 63;
    const int row  = blockIdx.x * 4 + wid;       // grid = N/4 blocks
    const float2 v = reinterpret_cast<const float2*>(z + (size_t)row * D)[lane];
    float ss = v.x * v.x + v.y * v.y;
    #pragma unroll
    for (int m = 1; m < 64; m <<= 1) ss += __shfl_xor(ss, m);
    const float inv = 1.0f / fmaxf(sqrtf(ss), 1e-8f);
    __hip_bfloat16 b0 = __float2bfloat16(v.x * inv);
    __hip_bfloat16 b1 = __float2bfloat16(v.y * inv);
    ushort2 o;
    o.x = *reinterpret_cast<ushort*>(&b0);
    o.y = *reinterpret_cast<ushort*>(&b1);
    reinterpret_cast<ushort2*>(zn + (size_t)row * D)[lane] = o;
    // self-dot of the ROUNDED vector (f32) — used to subtract self terms later
    const float f0 = __bfloat162float(b0), f1 = __bfloat162float(b1);
    float s2 = f0 * f0 + f1 * f1;
    #pragma unroll
    for (int m = 1; m < 64; m <<= 1) s2 += __shfl_xor(s2, m);
    if (lane == 0) dii[row] = s2;
}

// ---------------- Stage 0b: per-label sum vectors + histogram (deterministic) ----
// Block b handles rows [b*LROWS, (b+1)*LROWS). Thread d owns dim d exclusively
// (no races, fixed order -> deterministic). Thread d (d<100) also counts label d.
__global__ __launch_bounds__(128) void labelsum_kernel(const ushort* __restrict__ zn,
                                                       const int* __restrict__ y,
                                                       float* __restrict__ tpart,
                                                       float* __restrict__ cpart) {
    __shared__ float tl[NLBL][D];
    __shared__ int   ly[LROWS];
    const int d = threadIdx.x;                    // 0..127 = dim
    #pragma unroll 4
    for (int c = 0; c < NLBL; ++c) tl[c][d] = 0.0f;
    const int j0 = blockIdx.x * LROWS;
    for (int j = d; j < LROWS; j += 128) ly[j] = y[j0 + j];
    __syncthreads();
    float cl = 0.0f;
    for (int j = 0; j < LROWS; ++j) {
        const int c = ly[j];
        const float v =
            __bfloat162float(reinterpret_cast<const __hip_bfloat16*>(zn)[(size_t)(j0 + j) * D + d]);
        tl[c][d] += v;                            // thread-exclusive column: no race
        if (c == d) cl += 1.0f;
    }
    for (int c = 0; c < NLBL; ++c)
        tpart[((size_t)blockIdx.x * NLBL + c) * D + d] = tl[c][d];
    if (d < NLBL) cpart[blockIdx.x * NLBL + d] = cl;
}

__global__ __launch_bounds__(256) void reduce_t_kernel(const float* __restrict__ tpart,
                                                       const float* __restrict__ cpart,
                                                       float* __restrict__ t,
                                                       float* __restrict__ cnt) {
    const int idx = blockIdx.x * 256 + threadIdx.x;
    if (idx < NLBL * D) {
        float s = 0.0f;
        #pragma unroll
        for (int b = 0; b < LCH; ++b) s += tpart[(size_t)b * NLBL * D + idx];
        t[idx] = s;
    }
    if (idx < NLBL) {
        float s = 0.0f;
        #pragma unroll
        for (int b = 0; b < LCH; ++b) s += cpart[b * NLBL + idx];
        cnt[idx] = s;
    }
}

// ---------------- Stage 1: streaming MFMA, Z-only epilogue ----------------
__global__ __launch_bounds__(256) void supcon_main(const ushort* __restrict__ zn,
                                                   float* __restrict__ pZ) {
    const int wid  = threadIdx.x >> 6;
    const int lane = threadIdx.x & 63;
    const int g    = lane >> 4;      // 0..3 lane group
    const int lj   = lane & 15;      // col within tile / row within A-frag
    const int rowBlk = blockIdx.x % NRB;
    const int chunk  = blockIdx.x / NRB;
    const int rowBase = rowBlk * BM;

    // Preload A fragments: 4 M-tiles x 4 K-steps (lane row = lj)
    bf16x8 a[4][4];
    #pragma unroll
    for (int t = 0; t < 4; ++t) {
        const ushort* rp = zn + (size_t)(rowBase + t * 16 + lj) * D;
        #pragma unroll
        for (int s = 0; s < 4; ++s)
            a[t][s] = *reinterpret_cast<const bf16x8*>(rp + s * 32 + g * 8);
    }

    float Z[4][4];
    #pragma unroll
    for (int t = 0; t < 4; ++t)
        #pragma unroll
        for (int r = 0; r < 4; ++r) Z[t][r] = 0.0f;

    const f32x4 zero4 = {0.f, 0.f, 0.f, 0.f};
    const int jEnd = chunk * JCH + JCH;
    #pragma unroll 2
    for (int jt = chunk * JCH + wid * 16; jt < jEnd; jt += 64) {
        const ushort* jp = zn + (size_t)(jt + lj) * D;
        bf16x8 b[4];
        #pragma unroll
        for (int s = 0; s < 4; ++s)
            b[s] = *reinterpret_cast<const bf16x8*>(jp + s * 32 + g * 8);

        #pragma unroll
        for (int t = 0; t < 4; ++t) {
            f32x4 acc = zero4;
            #pragma unroll
            for (int s = 0; s < 4; ++s)
                acc = __builtin_amdgcn_mfma_f32_16x16x32_bf16(a[t][s], b[s], acc, 0, 0, 0);
            #pragma unroll
            for (int r = 0; r < 4; ++r)
                Z[t][r] += EXP2(fmaf(acc[r], K1F, K0F));   // exp(10*dot - 10)
        }
    }

    // Reduce across the 16 lanes of each group (cols of the wave's j slice)
    #pragma unroll
    for (int t = 0; t < 4; ++t)
        #pragma unroll
        for (int r = 0; r < 4; ++r)
            #pragma unroll
            for (int m = 1; m < 16; m <<= 1)
                Z[t][r] += __shfl_xor(Z[t][r], m);

    // Deterministic cross-wave combine via LDS
    __shared__ float red[4][BM];
    if (lj == 0) {
        #pragma unroll
        for (int t = 0; t < 4; ++t)
            #pragma unroll
            for (int r = 0; r < 4; ++r)
                red[wid][t * 16 + g * 4 + r] = Z[t][r];
    }
    __syncthreads();
    if (threadIdx.x < BM) {
        const int rl = threadIdx.x;
        pZ[chunk * N + rowBase + rl] =
            red[0][rl] + red[1][rl] + red[2][rl] + red[3][rl];
    }
}

// ---------------- Stage 2: finalize loss ----------------
// One wave per row: S_i = zn_i . t[y_i] - d_ii ; c_i = cnt[y_i]-1 ;
// Z_i = sum_k pZ - exp(10*d_ii-10) ; loss = -10*S/max(c,1) + [c>0](10+log Z)
__global__ __launch_bounds__(256) void supcon_finalize(const ushort* __restrict__ zn,
                                                       const int* __restrict__ y,
                                                       const float* __restrict__ pZ,
                                                       const float* __restrict__ dii,
                                                       const float* __restrict__ t,
                                                       const float* __restrict__ cnt,
                                                       float* __restrict__ out) {
    const int wid  = threadIdx.x >> 6;
    const int lane = threadIdx.x & 63;
    const int row  = blockIdx.x * 4 + wid;
    const int c    = y[row];
    const ushort2 u = reinterpret_cast<const ushort2*>(zn + (size_t)row * D)[lane];
    const float2 tv = reinterpret_cast<const float2*>(t + (size_t)c * D)[lane];
    __hip_bfloat16 h0, h1;
    *reinterpret_cast<ushort*>(&h0) = u.x;
    *reinterpret_cast<ushort*>(&h1) = u.y;
    float dot = __bfloat162float(h0) * tv.x + __bfloat162float(h1) * tv.y;
    #pragma unroll
    for (int m = 1; m < 64; m <<= 1) dot += __shfl_xor(dot, m);
    if (lane == 0) {
        float zs = 0.0f;
        #pragma unroll
        for (int k = 0; k < JC; ++k) zs += pZ[k * N + row];
        const float di = dii[row];
        const float zc = zs - EXP2(fmaf(di, K1F, K0F));   // remove self term
        const float cn = cnt[c] - 1.0f;                   // exclude self
        const float S  = dot - di;                        // exclude self
        const float denom = fmaxf(cn, 1.0f);
        const float lse   = 10.0f + logf(zc);
        out[row] = -(10.0f * S) / denom + (cn > 0.5f ? lse : 0.0f);
    }
}

extern "C" void kernel_launch(void* const* d_in, const int* in_sizes, int n_in,
                              void* d_out, int out_size, void* d_ws, size_t ws_size,
                              hipStream_t stream) {
    const float* z = (const float*)d_in[0];
    const int*   y = (const int*)d_in[1];
    float* out = (float*)d_out;

    // ws layout
    ushort* zn    = (ushort*)d_ws;                                  // 2 MB
    float*  dii   = (float*)((char*)d_ws + (size_t)N * D * 2);      // 32 KB
    float*  tpart = dii + N;                                        // 1.64 MB
    float*  cpart = tpart + (size_t)LCH * NLBL * D;                 // 12.8 KB
    float*  t     = cpart + (size_t)LCH * NLBL;                     // 51.2 KB
    float*  cnt   = t + (size_t)NLBL * D;                           // 400 B
    float*  pZ    = cnt + NLBL;                                     // 256 KB

    znorm_kernel<<<N / 4, 256, 0, stream>>>(z, zn, dii);
    labelsum_kernel<<<LCH, 128, 0, stream>>>(zn, y, tpart, cpart);
    reduce_t_kernel<<<(NLBL * D + 255) / 256, 256, 0, stream>>>(tpart, cpart, t, cnt);
    supcon_main<<<NRB * JC, 256, 0, stream>>>(zn, pZ);
    supcon_finalize<<<N / 4, 256, 0, stream>>>(zn, y, pZ, dii, t, cnt, out);
}